// Round 9
// baseline (384.092 us; speedup 1.0000x reference)
//
#include <hip/hip_runtime.h>

#define NINST 100
#define MLOG 28
#define IMG 800
#define LOGSZ (MLOG * MLOG) /* 784 */

// ws layout (32-bit words):
//  [0..99]    order (original index of n-th highest cls_prob)
//  [100..199] cls (0-based class of ordered instance)
//  [200..599] box (x0,y0,x1,y1 per ordered instance, int-truncated)
//  [600..699] msum
//  [800..899] slot_n (ordered-instance index for output slot s)
//  [900]      nkeep
//  [901]      npairs (written unconditionally by k_raster block 0)
//  [1024..]   bit-packed masks, stride 3648 words (12 x 304 rows), word col
//             aligned to GLOBAL word grid (word = x/32) so AND needs no shift.
//  [365824..] pair worklist (i, j, ovl) triplets, capacity 512.
//             (i,j) written by k_raster block 0 (class + box-overlap filter,
//             NO msum filter — empty masks give ovl=0 and are filtered in
//             the scan); ovl written by k_pairs_zero.
// All cross-kernel visibility via dispatch boundaries (free release/acquire)
// — rounds 3/4/5 showed intra-kernel cross-block sync costs MORE than the
// dispatches it removes (agent fences writeback/invalidate L2 mid-stream).
#define OFF_ORDER 0
#define OFF_CLS   100
#define OFF_BOX   200
#define OFF_MSUM  600
#define OFF_SLOT  800
#define OFF_NK    900
#define OFF_NPAIR 901
#define OFF_MASK  1024
#define ROWW      12
#define MSTRIDE   (ROWW * 304)
#define OFF_PAIRS (OFF_MASK + NINST * MSTRIDE) /* 365824 */
#define PAIR_CAP  512
#define ZTOT      (IMG * IMG * NINST / 4) /* 16e6 float4s to zero */
#define PBLK      64                      /* pair blocks (256 waves) */
#define ZBLKS     1984                    /* zero blocks; PBLK+ZBLKS = 2048 */

// Blocks rank (redundantly, from LDS) + rasterize bit-masks. Block 0 also
// builds the candidate pair worklist (~3us, hidden under the other 99
// blocks' rasterization) so k_pairs_zero needs no 10000-block launch.
__global__ __launch_bounds__(256) void k_raster(const float* __restrict__ mask_prob,
                                                const float* __restrict__ cls_prob,
                                                const float* __restrict__ rois,
                                                const int* __restrict__ cls_idx,
                                                int* __restrict__ ws) {
    int b = blockIdx.x, tid = threadIdx.x;
    __shared__ float s_p[NINST];
    __shared__ int s_order[NINST];
    __shared__ float lg[LOGSZ];
    __shared__ int red[256];
    __shared__ int s_c2[NINST];
    __shared__ int s_b2[4 * NINST];
    __shared__ int s_np;
    if (tid < NINST) s_p[tid] = cls_prob[tid];
    __syncthreads();
    if (tid < NINST) {
        float p = s_p[tid];
        int r = 0;
        for (int j = 0; j < NINST; j++) {
            float q = s_p[j];
            r += (q > p) || (q == p && j < tid); // stable argsort(-cls_prob)
        }
        s_order[r] = tid;
    }
    __syncthreads();
    int n = b;
    int orig = s_order[n];
    int x0 = (int)rois[4 * orig], y0 = (int)rois[4 * orig + 1];
    int x1 = (int)rois[4 * orig + 2], y1 = (int)rois[4 * orig + 3];
    if (b == 0) { // publish metadata + candidate worklist (block-uniform branch)
        if (tid == 0) s_np = 0;
        if (tid < NINST) {
            int o = s_order[tid];
            int cv = cls_idx[o] - 1;
            ws[OFF_ORDER + tid] = o;
            ws[OFF_CLS + tid] = cv;
            s_c2[tid] = cv;
#pragma unroll
            for (int k = 0; k < 4; k++) {
                int bv = (int)rois[4 * o + k];
                ws[OFF_BOX + 4 * tid + k] = bv;
                s_b2[4 * tid + k] = bv;
            }
        }
        __syncthreads();
        for (int c = tid; c < NINST * NINST; c += 256) {
            int i = c / NINST, j = c - i * NINST;
            if (i >= j) continue;
            if (s_c2[i] != s_c2[j]) continue;
            int ixs = max(s_b2[4 * i], 0), ixe = min(s_b2[4 * i + 2] + 1, IMG);
            int iys = max(s_b2[4 * i + 1], 0), iye = min(s_b2[4 * i + 3] + 1, IMG);
            int jxs = max(s_b2[4 * j], 0), jxe = min(s_b2[4 * j + 2] + 1, IMG);
            int jys = max(s_b2[4 * j + 1], 0), jye = min(s_b2[4 * j + 3] + 1, IMG);
            if (!(ixs < jxe && jxs < ixe && iys < jye && jys < iye)) continue;
            int k = atomicAdd(&s_np, 1);
            if (k < PAIR_CAP) {
                ws[OFF_PAIRS + 3 * k] = i;
                ws[OFF_PAIRS + 3 * k + 1] = j;
            }
        }
        __syncthreads();
        if (tid == 0) ws[OFF_NPAIR] = min(s_np, PAIR_CAP);
    }
    for (int i = tid; i < LOGSZ; i += 256) lg[i] = mask_prob[orig * LOGSZ + i];
    __syncthreads();
    int xs = max(x0, 0), xe = min(x1 + 1, IMG);
    int ys = max(y0, 0), ye = min(y1 + 1, IMG);
    int wx0 = xs >> 5, nw = ((xe + 31) >> 5) - wx0, nrows = ye - ys;
    float wf = fmaxf((float)(x1 - x0 + 1), 1.f), hf = fmaxf((float)(y1 - y0 + 1), 1.f);
    float rx = 28.f / wf, ry = 28.f / hf;
    unsigned* mb = (unsigned*)(ws + OFF_MASK) + n * MSTRIDE;
    int total = nrows * nw, cnt = 0;
    for (int t = tid; t < total; t += 256) {
        int row = t / nw, wc = t - row * nw;
        int y = ys + row;
        float sy = ((float)y - (float)y0 + 0.5f) * ry - 0.5f;
        sy = fminf(fmaxf(sy, 0.f), 27.f);
        int iy0 = (int)sy, iy1 = min(iy0 + 1, 27);
        float fy = sy - (float)iy0;
        const float* r0 = lg + iy0 * MLOG;
        const float* r1 = lg + iy1 * MLOG;
        unsigned bits = 0u;
        int xbase = (wx0 + wc) << 5;
        int j0 = max(xs - xbase, 0), j1 = min(xe - xbase, 32);
        for (int j = j0; j < j1; j++) {
            int xx = xbase + j;
            float sx = ((float)xx - (float)x0 + 0.5f) * rx - 0.5f;
            sx = fminf(fmaxf(sx, 0.f), 27.f);
            int ix0 = (int)sx, ix1 = min(ix0 + 1, 27);
            float fx = sx - (float)ix0;
            float val = (1.f - fy) * ((1.f - fx) * r0[ix0] + fx * r0[ix1]) +
                        fy * ((1.f - fx) * r1[ix0] + fx * r1[ix1]);
            bits |= (val > 0.f) ? (1u << j) : 0u;
        }
        mb[row * ROWW + wc] = bits;
        cnt += __popc(bits);
    }
    red[tid] = cnt;
    __syncthreads();
    for (int s = 128; s; s >>= 1) {
        if (tid < s) red[tid] += red[tid + s];
        __syncthreads();
    }
    if (tid == 0) ws[OFF_MSUM + n] = red[0];
}

// Blocks 0..63: wave-per-candidate AND-popcount over the compacted worklist
// (~60 entries) -> writes ovl into the pair list. No atomics, no 10000-block
// launch. Blocks 64..2047: grid-stride zero-fill of the 256 MB mask_energy
// output. Zero (~45us) fully overlaps pairs (~10us) in ONE dispatch; zero
// only needs to complete before k_box (two dispatch boundaries later).
__global__ __launch_bounds__(256) void k_pairs_zero(int* __restrict__ ws, float* __restrict__ out) {
    int b = blockIdx.x, tid = threadIdx.x;
    if (b >= PBLK) { // streaming zero path
        float4* z = (float4*)(out + NINST);
        for (size_t pi = (size_t)(b - PBLK) * 256 + tid; pi < (size_t)ZTOT; pi += (size_t)ZBLKS * 256)
            z[pi] = make_float4(0.f, 0.f, 0.f, 0.f);
        return;
    }
    int npair = min(ws[OFF_NPAIR], PAIR_CAP);
    int wid = (b << 2) | (tid >> 6), lane = tid & 63;
    const unsigned* maskbase = (const unsigned*)(ws + OFF_MASK);
    for (int k = wid; k < npair; k += (PBLK << 2)) {
        int i = ws[OFF_PAIRS + 3 * k], j = ws[OFF_PAIRS + 3 * k + 1];
        const int* bi = ws + OFF_BOX + 4 * i;
        const int* bj = ws + OFF_BOX + 4 * j;
        int ixs = max(bi[0], 0), ixe = min(bi[2] + 1, IMG);
        int iys = max(bi[1], 0), iye = min(bi[3] + 1, IMG);
        int jxs = max(bj[0], 0), jxe = min(bj[2] + 1, IMG);
        int jys = max(bj[1], 0), jye = min(bj[3] + 1, IMG);
        int iwx0 = ixs >> 5, jwx0 = jxs >> 5;
        int wlo = max(iwx0, jwx0);
        int whi = min((ixe + 31) >> 5, (jxe + 31) >> 5);
        int rlo = max(iys, jys), rhi = min(iye, jye);
        int nw = whi - wlo, nrows = rhi - rlo;
        const unsigned* mi = maskbase + i * MSTRIDE;
        const unsigned* mj = maskbase + j * MSTRIDE;
        int total = nrows * nw, cnt = 0;
        for (int t = lane; t < total; t += 64) {
            int row = t / nw, wc = t - row * nw;
            int y = rlo + row, w = wlo + wc;
            unsigned a = mi[(y - iys) * ROWW + (w - iwx0)];
            unsigned bb = mj[(y - jys) * ROWW + (w - jwx0)];
            cnt += __popc(a & bb);
        }
        for (int off = 32; off; off >>= 1) cnt += __shfl_down(cnt, off);
        if (lane == 0) ws[OFF_PAIRS + 3 * k + 2] = cnt;
    }
}

// Single wave, ZERO barriers (R8-verified): pairs preloaded from the global
// pair list into REGISTERS (8 slots/lane x 64 lanes = 512 cap, statically
// indexed). Per-n decision: 8 register compares + one 64-lane butterfly over
// (sum,max,cnt); keep set = two lane-uniform u64 masks. max_pair <= |union|
// <= sum_pair; int->float monotone => the reference's float compare is
// decided exactly when the bounds agree; rare ambiguous case: exact union
// popcount on this wave. Tiny 1-block dispatch (~10us) -> negligible gap.
__global__ __launch_bounds__(64) void k_scan(int* __restrict__ ws, float* __restrict__ out) {
    int lane = threadIdx.x;
    const unsigned* maskbase = (const unsigned*)(ws + OFF_MASK);
    __shared__ int s_msum[NINST];
    __shared__ int s_box[4 * NINST];
    __shared__ int s_cand[32];
    for (int i = lane; i < NINST; i += 64) s_msum[i] = ws[OFF_MSUM + i];
    for (int i = lane; i < 4 * NINST; i += 64) s_box[i] = ws[OFF_BOX + i];
    int npair = min(ws[OFF_NPAIR], PAIR_CAP);
    // pairs -> registers: slot s holds pair (lane + 64*s)
    int rpi[8], rpj[8], rpo[8];
#pragma unroll
    for (int s = 0; s < 8; s++) {
        int q = lane + (s << 6);
        rpi[s] = 0; rpo[s] = 0; rpj[s] = -1;
        if (q < npair) {
            rpi[s] = ws[OFF_PAIRS + 3 * q];
            rpj[s] = ws[OFF_PAIRS + 3 * q + 1];
            rpo[s] = ws[OFF_PAIRS + 3 * q + 2];
        }
    }
    // same-wave LDS/global RAW before the barrier-free loop
    asm volatile("s_waitcnt vmcnt(0) lgkmcnt(0)" ::: "memory");
    __builtin_amdgcn_sched_barrier(0);
    unsigned long long k0 = 0, k1 = 0; // keep set, lane-uniform
    for (int n = 0; n < NINST; n++) {
        int msum = s_msum[n];
        int lsum = 0, lmax = 0, lcnt = 0;
#pragma unroll
        for (int s = 0; s < 8; s++) {
            if (rpj[s] == n) {
                int pi = rpi[s];
                bool kb = (pi < 64) ? ((k0 >> pi) & 1ull) : ((k1 >> (pi - 64)) & 1ull);
                if (kb) { lsum += rpo[s]; lmax = max(lmax, rpo[s]); lcnt++; }
            }
        }
        for (int off = 32; off; off >>= 1) {
            lsum += __shfl_xor(lsum, off);
            lmax = max(lmax, __shfl_xor(lmax, off));
            lcnt += __shfl_xor(lcnt, off);
        }
        float thr = 0.3f * (float)msum;
        int keep;
        if (lcnt == 0 || (float)lsum <= thr) keep = (msum > 0);
        else if ((float)lmax > thr) keep = 0;
        else { // max <= thr < sum: exact union needed (rare), same wave
            int nc = 0;
#pragma unroll
            for (int s = 0; s < 8; s++) {
                bool p = false; int piv = 0;
                if (rpj[s] == n) {
                    piv = rpi[s];
                    p = (piv < 64) ? ((k0 >> piv) & 1ull) : ((k1 >> (piv - 64)) & 1ull);
                }
                unsigned long long m = __ballot(p);
                int pos = nc + __popcll(m & ((1ull << lane) - 1ull));
                if (p && pos < 32) s_cand[pos] = piv;
                nc += __popcll(m);
            }
            nc = min(nc, 32);
            // same-wave LDS RAW: force write completion + no reordering
            asm volatile("s_waitcnt lgkmcnt(0)" ::: "memory");
            __builtin_amdgcn_sched_barrier(0);
            int nxs = max(s_box[4 * n], 0), nxe = min(s_box[4 * n + 2] + 1, IMG);
            int nys = max(s_box[4 * n + 1], 0), nye = min(s_box[4 * n + 3] + 1, IMG);
            int wx0 = nxs >> 5, nwrd = ((nxe + 31) >> 5) - wx0, nrows = nye - nys;
            const unsigned* mn = maskbase + n * MSTRIDE;
            int total = nrows * nwrd, ovl = 0;
            for (int t2 = lane; t2 < total; t2 += 64) {
                int row = t2 / nwrd, wc = t2 - row * nwrd;
                unsigned bits = mn[row * ROWW + wc];
                if (!bits) continue;
                int y = nys + row, wa = wx0 + wc;
                unsigned img = 0;
                for (int k = 0; k < nc; k++) {
                    int m2 = s_cand[k];
                    int mys = max(s_box[4 * m2 + 1], 0), mye = min(s_box[4 * m2 + 3] + 1, IMG);
                    int mxs = max(s_box[4 * m2], 0), mxe = min(s_box[4 * m2 + 2] + 1, IMG);
                    int mwx0 = mxs >> 5, mnw = ((mxe + 31) >> 5) - mwx0;
                    int rr = y - mys, cc = wa - mwx0;
                    if (rr >= 0 && rr < (mye - mys) && cc >= 0 && cc < mnw)
                        img |= maskbase[m2 * MSTRIDE + rr * ROWW + cc];
                }
                ovl += __popc(bits & img);
            }
            for (int off = 32; off; off >>= 1) ovl += __shfl_xor(ovl, off);
            keep = (msum > 0) && ((float)ovl <= thr);
        }
        if (keep) { if (n < 64) k0 |= 1ull << n; else k1 |= 1ull << (n - 64); }
    }
    if (lane == 0) {
        int nk = 0;
        for (int n = 0; n < NINST; n++) {
            bool kb = (n < 64) ? ((k0 >> n) & 1ull) : ((k1 >> (n - 64)) & 1ull);
            if (kb) {
                ws[OFF_SLOT + nk] = n;
                out[nk] = (float)ws[OFF_ORDER + n];
                nk++;
            }
        }
        ws[OFF_NK] = nk;
        for (int s2 = nk; s2 < NINST; s2++) out[s2] = -1.f;
    }
}

// Writes kept boxes' interiors only (output already zeroed by k_pairs_zero).
__global__ __launch_bounds__(256) void k_box(const float* __restrict__ mask_prob,
                                             const int* __restrict__ ws,
                                             float* __restrict__ out) {
    int slot = blockIdx.y, tid = threadIdx.x;
    if (slot >= ws[OFF_NK]) return; // uniform per block
    int n = ws[OFF_SLOT + slot];
    const int* box = ws + OFF_BOX + 4 * n;
    int x0 = box[0], y0 = box[1], x1 = box[2], y1 = box[3];
    int xs = max(x0, 0), xe = min(x1 + 1, IMG);
    int ys = max(y0, 0), ye = min(y1 + 1, IMG);
    int xa = xs & ~3;
    int w4 = (xe - xa + 3) >> 2;
    int rows = ye - ys;
    int total = rows * w4;
    __shared__ float lg[LOGSZ];
    int orig = ws[OFF_ORDER + n];
    for (int i = tid; i < LOGSZ; i += 256) lg[i] = mask_prob[orig * LOGSZ + i];
    __syncthreads();
    float wf = fmaxf((float)(x1 - x0 + 1), 1.f), hf = fmaxf((float)(y1 - y0 + 1), 1.f);
    float rx = 28.f / wf, ry = 28.f / hf;
    float* base = out + NINST + (size_t)slot * (IMG * IMG);
    for (int t = blockIdx.x * 256 + tid; t < total; t += gridDim.x * 256) {
        int row = t / w4, c4 = t - row * w4;
        int y = ys + row, xb = xa + (c4 << 2);
        float sy = ((float)y - (float)y0 + 0.5f) * ry - 0.5f;
        sy = fminf(fmaxf(sy, 0.f), 27.f);
        int iy0 = (int)sy, iy1 = min(iy0 + 1, 27);
        float fy = sy - (float)iy0;
        const float* r0 = lg + iy0 * MLOG;
        const float* r1 = lg + iy1 * MLOG;
        float v[4];
#pragma unroll
        for (int j = 0; j < 4; j++) {
            int xx = xb + j;
            float val = 0.f;
            if (xx >= xs && xx < xe) {
                float sx = ((float)xx - (float)x0 + 0.5f) * rx - 0.5f;
                sx = fminf(fmaxf(sx, 0.f), 27.f);
                int ix0 = (int)sx, ix1 = min(ix0 + 1, 27);
                float fx = sx - (float)ix0;
                val = (1.f - fy) * ((1.f - fx) * r0[ix0] + fx * r0[ix1]) +
                      fy * ((1.f - fx) * r1[ix0] + fx * r1[ix1]);
            }
            v[j] = val;
        }
        *(float4*)(base + (size_t)y * IMG + xb) = make_float4(v[0], v[1], v[2], v[3]);
    }
}

extern "C" void kernel_launch(void* const* d_in, const int* in_sizes, int n_in,
                              void* d_out, int out_size, void* d_ws, size_t ws_size,
                              hipStream_t stream) {
    const float* rois      = (const float*)d_in[0];
    const float* cls_prob  = (const float*)d_in[1];
    const float* mask_prob = (const float*)d_in[2];
    const int*   cls_idx   = (const int*)d_in[3];
    int* ws = (int*)d_ws;
    float* out = (float*)d_out;

    k_raster<<<dim3(NINST), dim3(256), 0, stream>>>(mask_prob, cls_prob, rois, cls_idx, ws);
    // blocks 0..63 = pair popcounts over compacted worklist; 64..2047 = zero stream
    k_pairs_zero<<<dim3(PBLK + ZBLKS), dim3(256), 0, stream>>>(ws, out);
    k_scan<<<dim3(1), dim3(64), 0, stream>>>(ws, out);
    // max box 301x301 -> rows*w4 <= 301*77 = 23177 <= 91*256
    k_box<<<dim3(91, NINST), dim3(256), 0, stream>>>(mask_prob, ws, out);
}

// Round 10
// 329.661 us; speedup vs baseline: 1.1651x; 1.1651x over previous
//
#include <hip/hip_runtime.h>

#define NINST 100
#define MLOG 28
#define IMG 800
#define LOGSZ (MLOG * MLOG) /* 784 */

// ws layout (32-bit words):
//  [0..99]    order (original index of n-th highest cls_prob)
//  [100..199] cls (0-based class of ordered instance)
//  [200..599] box (x0,y0,x1,y1 per ordered instance, int-truncated)
//  [600..699] msum
//  [800..899] slot_n (ordered-instance index for output slot s)
//  [900]      nkeep
//  [901]      npairs
//  [1024..]   bit-packed masks, stride 3648 words (12 x 304 rows), word col
//             aligned to GLOBAL word grid (word = x/32) so AND needs no shift.
//  [365824..] pair list (i, j, ovl) triplets, capacity 512
// EMPIRICAL OPTIMUM over 9 structural variants (332 us; fusion with flags
// 358-377, grid barriers 625, pairs-overlap restructure 384). The chain is
// bound by harness poison fills (~195us at 83% HBM peak), the mandatory
// 256 MB output write (~40us), and launch-gap floor; residual slack < noise.
#define OFF_ORDER 0
#define OFF_CLS   100
#define OFF_BOX   200
#define OFF_MSUM  600
#define OFF_SLOT  800
#define OFF_NK    900
#define OFF_NPAIR 901
#define OFF_MASK  1024
#define ROWW      12
#define MSTRIDE   (ROWW * 304)
#define OFF_PAIRS (OFF_MASK + NINST * MSTRIDE) /* 365824 */
#define PAIR_CAP  512
#define ZTOT      (IMG * IMG * NINST / 4) /* 16e6 float4s to zero */
#define ZBLKS     4096

// Blocks rank (redundantly, from LDS) + rasterize bit-masks.
__global__ __launch_bounds__(256) void k_raster(const float* __restrict__ mask_prob,
                                                const float* __restrict__ cls_prob,
                                                const float* __restrict__ rois,
                                                const int* __restrict__ cls_idx,
                                                int* __restrict__ ws) {
    int b = blockIdx.x, tid = threadIdx.x;
    __shared__ float s_p[NINST];
    __shared__ int s_order[NINST];
    __shared__ float lg[LOGSZ];
    __shared__ int red[256];
    if (tid < NINST) s_p[tid] = cls_prob[tid];
    __syncthreads();
    if (tid < NINST) {
        float p = s_p[tid];
        int r = 0;
        for (int j = 0; j < NINST; j++) {
            float q = s_p[j];
            r += (q > p) || (q == p && j < tid); // stable argsort(-cls_prob)
        }
        s_order[r] = tid;
    }
    __syncthreads();
    int n = b;
    int orig = s_order[n];
    int x0 = (int)rois[4 * orig], y0 = (int)rois[4 * orig + 1];
    int x1 = (int)rois[4 * orig + 2], y1 = (int)rois[4 * orig + 3];
    if (b == 0) { // publish metadata for downstream kernels
        if (tid == 0) ws[OFF_NPAIR] = 0;
        if (tid < NINST) {
            int o = s_order[tid];
            ws[OFF_ORDER + tid] = o;
            ws[OFF_CLS + tid] = cls_idx[o] - 1;
#pragma unroll
            for (int k = 0; k < 4; k++)
                ws[OFF_BOX + 4 * tid + k] = (int)rois[4 * o + k];
        }
    }
    for (int i = tid; i < LOGSZ; i += 256) lg[i] = mask_prob[orig * LOGSZ + i];
    __syncthreads();
    int xs = max(x0, 0), xe = min(x1 + 1, IMG);
    int ys = max(y0, 0), ye = min(y1 + 1, IMG);
    int wx0 = xs >> 5, nw = ((xe + 31) >> 5) - wx0, nrows = ye - ys;
    float wf = fmaxf((float)(x1 - x0 + 1), 1.f), hf = fmaxf((float)(y1 - y0 + 1), 1.f);
    float rx = 28.f / wf, ry = 28.f / hf;
    unsigned* mb = (unsigned*)(ws + OFF_MASK) + n * MSTRIDE;
    int total = nrows * nw, cnt = 0;
    for (int t = tid; t < total; t += 256) {
        int row = t / nw, wc = t - row * nw;
        int y = ys + row;
        float sy = ((float)y - (float)y0 + 0.5f) * ry - 0.5f;
        sy = fminf(fmaxf(sy, 0.f), 27.f);
        int iy0 = (int)sy, iy1 = min(iy0 + 1, 27);
        float fy = sy - (float)iy0;
        const float* r0 = lg + iy0 * MLOG;
        const float* r1 = lg + iy1 * MLOG;
        unsigned bits = 0u;
        int xbase = (wx0 + wc) << 5;
        int j0 = max(xs - xbase, 0), j1 = min(xe - xbase, 32);
        for (int j = j0; j < j1; j++) {
            int xx = xbase + j;
            float sx = ((float)xx - (float)x0 + 0.5f) * rx - 0.5f;
            sx = fminf(fmaxf(sx, 0.f), 27.f);
            int ix0 = (int)sx, ix1 = min(ix0 + 1, 27);
            float fx = sx - (float)ix0;
            float val = (1.f - fy) * ((1.f - fx) * r0[ix0] + fx * r0[ix1]) +
                        fy * ((1.f - fx) * r1[ix0] + fx * r1[ix1]);
            bits |= (val > 0.f) ? (1u << j) : 0u;
        }
        mb[row * ROWW + wc] = bits;
        cnt += __popc(bits);
    }
    red[tid] = cnt;
    __syncthreads();
    for (int s = 128; s; s >>= 1) {
        if (tid < s) red[tid] += red[tid + s];
        __syncthreads();
    }
    if (tid == 0) ws[OFF_MSUM + n] = red[0];
}

// One wave per (i,j) pair, i<j: if same class, both non-empty, boxes overlap,
// compute popcount(mask_i & mask_j) and append to compact pair list.
// NOTE: appends even when cnt==0 — the scan's candidate enumeration relies
// on the pair list being the exact candidate set.
__global__ __launch_bounds__(64) void k_pairs(int* __restrict__ ws) {
    int i = blockIdx.x, j = blockIdx.y, tid = threadIdx.x;
    if (i >= j) return;
    if (ws[OFF_CLS + i] != ws[OFF_CLS + j]) return;
    if (ws[OFF_MSUM + i] == 0 || ws[OFF_MSUM + j] == 0) return;
    const int* bi = ws + OFF_BOX + 4 * i;
    const int* bj = ws + OFF_BOX + 4 * j;
    int ixs = max(bi[0], 0), ixe = min(bi[2] + 1, IMG);
    int iys = max(bi[1], 0), iye = min(bi[3] + 1, IMG);
    int jxs = max(bj[0], 0), jxe = min(bj[2] + 1, IMG);
    int jys = max(bj[1], 0), jye = min(bj[3] + 1, IMG);
    if (!(ixs < jxe && jxs < ixe && iys < jye && jys < iye)) return;
    int iwx0 = ixs >> 5, jwx0 = jxs >> 5;
    int wlo = max(iwx0, jwx0);
    int whi = min((ixe + 31) >> 5, (jxe + 31) >> 5);
    int rlo = max(iys, jys), rhi = min(iye, jye);
    int nw = whi - wlo, nrows = rhi - rlo;
    const unsigned* mi = (const unsigned*)(ws + OFF_MASK) + i * MSTRIDE;
    const unsigned* mj = (const unsigned*)(ws + OFF_MASK) + j * MSTRIDE;
    int total = nrows * nw, cnt = 0;
    for (int t = tid; t < total; t += 64) {
        int row = t / nw, wc = t - row * nw;
        int y = rlo + row, w = wlo + wc;
        unsigned a = mi[(y - iys) * ROWW + (w - iwx0)];
        unsigned b = mj[(y - jys) * ROWW + (w - jwx0)];
        cnt += __popc(a & b);
    }
    for (int off = 32; off; off >>= 1) cnt += __shfl_down(cnt, off);
    if (tid == 0) {
        int k = atomicAdd(ws + OFF_NPAIR, 1);
        if (k < PAIR_CAP) {
            ws[OFF_PAIRS + 3 * k] = i;
            ws[OFF_PAIRS + 3 * k + 1] = j;
            ws[OFF_PAIRS + 3 * k + 2] = cnt;
        }
    }
}

// Block 0: sequential keep scan driven directly by the pair list (the pair
// list IS the candidate set: same class, boxes overlap, both non-empty).
// max_pair <= |union ovl| <= sum_pair; int->float is monotone so the
// reference's float compare is decided exactly when bounds agree; rare
// ambiguous case falls back to block-parallel union popcount.
// Blocks 1..4096: grid-stride zero-fill of the whole 256 MB mask_energy
// output — overlaps the otherwise single-block (255-CUs-idle) scan.
// No inter-block dependency: outputs are disjoint, order-independent.
__global__ __launch_bounds__(256) void k_scan_zero(int* __restrict__ ws, float* __restrict__ out) {
    int b = blockIdx.x, tid = threadIdx.x;
    if (b > 0) { // streaming zero path
        float4* z = (float4*)(out + NINST);
        for (size_t pi = (size_t)(b - 1) * 256 + tid; pi < (size_t)ZTOT; pi += (size_t)ZBLKS * 256)
            z[pi] = make_float4(0.f, 0.f, 0.f, 0.f);
        return;
    }
    __shared__ int s_box[4 * NINST];
    __shared__ int s_msum[NINST];
    __shared__ int s_keep[NINST];
    __shared__ int s_cand[32];
    __shared__ int s_ncand, s_sum, s_max, s_need;
    __shared__ int s_pi[PAIR_CAP], s_pj[PAIR_CAP], s_po[PAIR_CAP];
    __shared__ int red[256];
    for (int i = tid; i < NINST; i += 256) s_msum[i] = ws[OFF_MSUM + i];
    for (int i = tid; i < 4 * NINST; i += 256) s_box[i] = ws[OFF_BOX + i];
    int npair = min(ws[OFF_NPAIR], PAIR_CAP);
    for (int i = tid; i < npair; i += 256) {
        s_pi[i] = ws[OFF_PAIRS + 3 * i];
        s_pj[i] = ws[OFF_PAIRS + 3 * i + 1];
        s_po[i] = ws[OFF_PAIRS + 3 * i + 2];
    }
    const unsigned* maskbase = (const unsigned*)(ws + OFF_MASK);
    __syncthreads();

    for (int n = 0; n < NINST; n++) {
        if (tid == 0) { s_ncand = 0; s_sum = 0; s_max = 0; }
        __syncthreads(); // also publishes s_keep[n-1]
        for (int q = tid; q < npair; q += 256) {
            if (s_pj[q] == n && s_keep[s_pi[q]]) { // pi < pj == n: s_keep valid
                int k = atomicAdd(&s_ncand, 1);
                if (k < 32) s_cand[k] = s_pi[q];
                atomicAdd(&s_sum, s_po[q]);
                atomicMax(&s_max, s_po[q]);
            }
        }
        __syncthreads();
        if (tid == 0) {
            int msum = s_msum[n];
            float t = 0.3f * (float)msum;
            int keep, need = 0;
            if (s_ncand == 0 || (float)s_sum <= t) keep = (msum > 0);
            else if ((float)s_max > t) keep = 0;
            else { keep = 0; need = 1; } // max <= t < sum: exact union needed
            s_keep[n] = keep;
            s_need = need;
        }
        __syncthreads();
        if (s_need) { // rare: >=2 kept same-class overlapping predecessors, bounds disagree
            int nc = min(s_ncand, 32);
            int nxs = max(s_box[4 * n], 0), nxe = min(s_box[4 * n + 2] + 1, IMG);
            int nys = max(s_box[4 * n + 1], 0), nye = min(s_box[4 * n + 3] + 1, IMG);
            int wx0 = nxs >> 5, nw = ((nxe + 31) >> 5) - wx0, nrows = nye - nys;
            const unsigned* mn = maskbase + n * MSTRIDE;
            int total = nrows * nw, ovl = 0;
            for (int t2 = tid; t2 < total; t2 += 256) {
                int row = t2 / nw, wc = t2 - row * nw;
                unsigned bits = mn[row * ROWW + wc];
                if (!bits) continue;
                int y = nys + row, wa = wx0 + wc;
                unsigned img = 0;
                for (int k = 0; k < nc; k++) {
                    int m = s_cand[k];
                    int mys = max(s_box[4 * m + 1], 0), mye = min(s_box[4 * m + 3] + 1, IMG);
                    int mxs = max(s_box[4 * m], 0), mxe = min(s_box[4 * m + 2] + 1, IMG);
                    int mwx0 = mxs >> 5, mnw = ((mxe + 31) >> 5) - mwx0;
                    int rr = y - mys, cc = wa - mwx0;
                    if (rr >= 0 && rr < (mye - mys) && cc >= 0 && cc < mnw)
                        img |= maskbase[m * MSTRIDE + rr * ROWW + cc];
                }
                ovl += __popc(bits & img);
            }
            red[tid] = ovl;
            __syncthreads();
            for (int s = 128; s; s >>= 1) {
                if (tid < s) red[tid] += red[tid + s];
                __syncthreads();
            }
            if (tid == 0) {
                int msum = s_msum[n];
                s_keep[n] = (msum > 0) && ((float)red[0] <= 0.3f * (float)msum);
            }
        }
    }
    __syncthreads();
    if (tid == 0) {
        int nk = 0;
        for (int n = 0; n < NINST; n++) {
            if (s_keep[n]) {
                ws[OFF_SLOT + nk] = n;
                out[nk] = (float)ws[OFF_ORDER + n];
                nk++;
            }
        }
        ws[OFF_NK] = nk;
        for (int s = nk; s < NINST; s++) out[s] = -1.f;
    }
}

// Writes kept boxes' interiors only (output already zeroed by k_scan_zero).
__global__ __launch_bounds__(256) void k_box(const float* __restrict__ mask_prob,
                                             const int* __restrict__ ws,
                                             float* __restrict__ out) {
    int slot = blockIdx.y, tid = threadIdx.x;
    if (slot >= ws[OFF_NK]) return; // uniform per block
    int n = ws[OFF_SLOT + slot];
    const int* box = ws + OFF_BOX + 4 * n;
    int x0 = box[0], y0 = box[1], x1 = box[2], y1 = box[3];
    int xs = max(x0, 0), xe = min(x1 + 1, IMG);
    int ys = max(y0, 0), ye = min(y1 + 1, IMG);
    int xa = xs & ~3;
    int w4 = (xe - xa + 3) >> 2;
    int rows = ye - ys;
    int total = rows * w4;
    __shared__ float lg[LOGSZ];
    int orig = ws[OFF_ORDER + n];
    for (int i = tid; i < LOGSZ; i += 256) lg[i] = mask_prob[orig * LOGSZ + i];
    __syncthreads();
    float wf = fmaxf((float)(x1 - x0 + 1), 1.f), hf = fmaxf((float)(y1 - y0 + 1), 1.f);
    float rx = 28.f / wf, ry = 28.f / hf;
    float* base = out + NINST + (size_t)slot * (IMG * IMG);
    for (int t = blockIdx.x * 256 + tid; t < total; t += gridDim.x * 256) {
        int row = t / w4, c4 = t - row * w4;
        int y = ys + row, xb = xa + (c4 << 2);
        float sy = ((float)y - (float)y0 + 0.5f) * ry - 0.5f;
        sy = fminf(fmaxf(sy, 0.f), 27.f);
        int iy0 = (int)sy, iy1 = min(iy0 + 1, 27);
        float fy = sy - (float)iy0;
        const float* r0 = lg + iy0 * MLOG;
        const float* r1 = lg + iy1 * MLOG;
        float v[4];
#pragma unroll
        for (int j = 0; j < 4; j++) {
            int xx = xb + j;
            float val = 0.f;
            if (xx >= xs && xx < xe) {
                float sx = ((float)xx - (float)x0 + 0.5f) * rx - 0.5f;
                sx = fminf(fmaxf(sx, 0.f), 27.f);
                int ix0 = (int)sx, ix1 = min(ix0 + 1, 27);
                float fx = sx - (float)ix0;
                val = (1.f - fy) * ((1.f - fx) * r0[ix0] + fx * r0[ix1]) +
                      fy * ((1.f - fx) * r1[ix0] + fx * r1[ix1]);
            }
            v[j] = val;
        }
        *(float4*)(base + (size_t)y * IMG + xb) = make_float4(v[0], v[1], v[2], v[3]);
    }
}

extern "C" void kernel_launch(void* const* d_in, const int* in_sizes, int n_in,
                              void* d_out, int out_size, void* d_ws, size_t ws_size,
                              hipStream_t stream) {
    const float* rois      = (const float*)d_in[0];
    const float* cls_prob  = (const float*)d_in[1];
    const float* mask_prob = (const float*)d_in[2];
    const int*   cls_idx   = (const int*)d_in[3];
    int* ws = (int*)d_ws;
    float* out = (float*)d_out;

    k_raster<<<dim3(NINST), dim3(256), 0, stream>>>(mask_prob, cls_prob, rois, cls_idx, ws);
    k_pairs<<<dim3(NINST, NINST), dim3(64), 0, stream>>>(ws);
    // block 0 = serial keep scan; blocks 1..4096 = 256 MB zero stream (overlapped)
    k_scan_zero<<<dim3(1 + ZBLKS), dim3(256), 0, stream>>>(ws, out);
    // max box 301x301 -> rows*w4 <= 301*77 = 23177 <= 91*256
    k_box<<<dim3(91, NINST), dim3(256), 0, stream>>>(mask_prob, ws, out);
}